// Round 14
// baseline (520.506 us; speedup 1.0000x reference)
//
#include <hip/hip_runtime.h>
#include <hip/hip_fp16.h>
#include <stdint.h>

#define B_ROWS 4096
#define N_PAT  8192
#define N_NEU  1024

typedef _Float16 f16x8 __attribute__((ext_vector_type(8)));
typedef _Float16 f16x4 __attribute__((ext_vector_type(4)));
typedef float    f32x4 __attribute__((ext_vector_type(4)));

__device__ __forceinline__ f32x4 mfma16(f16x8 a, f16x8 b, f32x4 c) {
  return __builtin_amdgcn_mfma_f32_16x16x32_f16(a, b, c, 0, 0, 0);
}

// ---------------- fp32 -> fp16 elementwise convert (vectorized) ----------------
__global__ __launch_bounds__(256) void convert_f32_f16(
    const float* __restrict__ in, _Float16* __restrict__ out, int n4) {
  int idx    = blockIdx.x * 256 + threadIdx.x;
  int stride = gridDim.x * 256;
  for (int i = idx; i < n4; i += stride) {
    float4 v = reinterpret_cast<const float4*>(in)[i];
    f16x4 h  = { (_Float16)v.x, (_Float16)v.y, (_Float16)v.z, (_Float16)v.w };
    reinterpret_cast<f16x4*>(out)[i] = h;
  }
}

// ------- patterns: single read -> Pb (f16, same layout) + PbT (f16, transposed) -------
__global__ __launch_bounds__(256) void prep_patterns(
    const float* __restrict__ in, _Float16* __restrict__ pb,
    _Float16* __restrict__ pbt, int rows, int cols) {
  __shared__ float tile[32][33];
  int c0 = blockIdx.x * 32, r0 = blockIdx.y * 32;
  int tx = threadIdx.x, ty = threadIdx.y;  // 32 x 8
  #pragma unroll
  for (int i = 0; i < 32; i += 8) {
    float v = in[(size_t)(r0 + ty + i) * cols + c0 + tx];
    tile[ty + i][tx] = v;
    pb[(size_t)(r0 + ty + i) * cols + c0 + tx] = (_Float16)v;
  }
  __syncthreads();
  #pragma unroll
  for (int i = 0; i < 32; i += 8)
    pbt[(size_t)(c0 + ty + i) * rows + r0 + tx] = (_Float16)tile[tx][ty + i];
}

// ---------------- async global->LDS, 16B per lane, wave-uniform LDS base ----------------
__device__ __forceinline__ void gload_lds16(const _Float16* g, _Float16* l) {
  __builtin_amdgcn_global_load_lds(
      (const __attribute__((address_space(1))) uint32_t*)g,
      (__attribute__((address_space(3))) uint32_t*)l, 16, 0, 0);
}

// ==== 256x256, 8 waves, XOR LDS, counted gate + 2-half DRIFT schedule ====
// r13 (fine interleave, 5 barriers/K-tile) kept waves in phase-lockstep: LDS-read
// and MFMA pipes (co-critical, ~2760 vs ~2483 cyc/tile) ping-ponged at CU level.
// This version merges the 4 phases into 2 halves with ONE mid-tile barrier, so
// waves drift within each half (one wave's ds_reads overlap another's MFMAs)
// while the r12/13 stage choreography + counted vmcnt gate is preserved.
// Ledger: A(t+1)->s^1 at half-0 start (A-region of s^1 dead since gate).
//   mid-bar: each wave passed half-0 MFMAs => its bf reads retired => staging
//   B(t+2) into slot-s B-region is safe; half-1 af reads touch A-region only.
//   Next gate's BAR separates this tile's af reads (each fed an MFMA => retired)
//   from tile t+1's A(t+2)->slot-s staging. Gate: vmcnt(4) = A(t) landed,
//   B(t+1)... (4 newest = B(t+2) outstanding) - never drains to 0 mid-loop.
template <typename OUT_T>
__global__ __launch_bounds__(512, 2) void gemm_x(
    const _Float16* __restrict__ A, const _Float16* __restrict__ Bt,
    OUT_T* __restrict__ C, int M, int N, int K, int KS) {
  __shared__ _Float16 lds[2][2][256 * 64];  // [slot][A/B][row*64]
  const int t    = threadIdx.x;
  const int lane = t & 63;
  const int w    = t >> 6;       // wave 0..7
  const int wr   = w >> 2;       // M half -> wave tile 128x64
  const int wc   = w & 3;        // N quarter
  const int m0   = blockIdx.x * 256;
  const int n0   = blockIdx.y * 256;
  const int k0   = blockIdx.z * KS;

  // staging: issue j covers rows j*64 + w*8 + (lane>>3); source granule pre-swizzled
  // (lane&7)^(row&7): LDS granule column XOR'd while the global segment per 8-lane
  // row-group stays a contiguous 128B line (keep staging coalesced - r8 lesson).
  const int srow  = w * 8 + (lane >> 3);
  const int sgran = ((lane & 7) ^ ((lane >> 3) & 7)) * 8;
  const _Float16* sA = A  + (size_t)(m0 + srow) * K + sgran + k0;
  const _Float16* sB = Bt + (size_t)(n0 + srow) * K + sgran + k0;
  const size_t rj = (size_t)64 * K;   // row jump per issue (64 rows)
  const int ldst  = w * 512;          // wave-uniform LDS elem offset within issue chunk

  const int lrow = lane & 15;  // fragment row (A) / col (B)
  const int kg   = lane >> 4;  // k-group 0..3
  const int NT   = KS >> 6;

  f32x4 acc[8][4] = {};

  auto stageAh = [&](int slot, int kt, int h) {  // half h = rows h*128..h*128+127
    gload_lds16(sA + (size_t)(2 * h)     * rj + kt, &lds[slot][0][(2 * h)     * 4096 + ldst]);
    gload_lds16(sA + (size_t)(2 * h + 1) * rj + kt, &lds[slot][0][(2 * h + 1) * 4096 + ldst]);
  };
  auto stageBh = [&](int slot, int kt, int h) {
    gload_lds16(sB + (size_t)(2 * h)     * rj + kt, &lds[slot][1][(2 * h)     * 4096 + ldst]);
    gload_lds16(sB + (size_t)(2 * h + 1) * rj + kt, &lds[slot][1][(2 * h + 1) * 4096 + ldst]);
  };

#define READ_AF2(dst, MI0)                                                                  \
  { const int ar0 = wr * 128 + (MI0) * 16 + lrow;                                           \
    dst[(MI0) & 3][0] = *reinterpret_cast<const f16x8*>(&As[ar0 * 64 + (((kg) ^ (ar0 & 7)) * 8)]);     \
    dst[(MI0) & 3][1] = *reinterpret_cast<const f16x8*>(&As[ar0 * 64 + (((4 + kg) ^ (ar0 & 7)) * 8)]); }

#define MFMA_HALF(MI0, src)                                                   \
  { __builtin_amdgcn_s_setprio(1);                                            \
    _Pragma("unroll")                                                         \
    for (int mi = 0; mi < 4; ++mi) {                                          \
      _Pragma("unroll")                                                       \
      for (int ni = 0; ni < 4; ++ni) {                                        \
        acc[(MI0) + mi][ni] = mfma16(src[mi][0], bf[ni][0], acc[(MI0) + mi][ni]); \
        acc[(MI0) + mi][ni] = mfma16(src[mi][1], bf[ni][1], acc[(MI0) + mi][ni]); \
      }                                                                       \
    }                                                                         \
    __builtin_amdgcn_s_setprio(0); }

#define BAR() asm volatile("s_barrier" ::: "memory")

  // ---- prologue: B(0),A(0) -> slot0 ; B(1) -> slot1  (12 loads)
  stageBh(0, 0, 0);  stageBh(0, 0, 1);
  stageAh(0, 0, 0);  stageAh(0, 0, 1);
  stageBh(1, 64, 0); stageBh(1, 64, 1);

  for (int tt = 0; tt < NT; ++tt) {
    const int s = tt & 1;
    // ---- per-K-tile gate (counted; never 0 until the last tile)
    if (tt + 1 < NT) asm volatile("s_waitcnt vmcnt(4)" ::: "memory");
    else             asm volatile("s_waitcnt vmcnt(0)" ::: "memory");
    BAR();

    const _Float16* As = lds[s][0];
    const _Float16* Bs = lds[s][1];
    const int ktA  = (tt + 1) << 6;
    const int ktB  = (tt + 2) << 6;

    // ---- half 0: stage A(t+1); read bf + af(mi 0-3); 32 MFMAs. Waves drift.
    if (tt + 1 < NT) { stageAh(s ^ 1, ktA, 0); stageAh(s ^ 1, ktA, 1); }
    f16x8 bf[4][2], af[4][2];
    #pragma unroll
    for (int ni = 0; ni < 4; ++ni) {
      const int br = wc * 64 + ni * 16 + lrow;
      bf[ni][0] = *reinterpret_cast<const f16x8*>(&Bs[br * 64 + (((kg) ^ (br & 7)) * 8)]);
      bf[ni][1] = *reinterpret_cast<const f16x8*>(&Bs[br * 64 + (((4 + kg) ^ (br & 7)) * 8)]);
    }
    READ_AF2(af, 0) READ_AF2(af, 1) READ_AF2(af, 2) READ_AF2(af, 3)
    MFMA_HALF(0, af)

    // ---- mid-bar: all waves' bf reads retired (each fed a half-0 MFMA)
    BAR();

    // ---- half 1: stage B(t+2) into slot s (B-region; bf reads done); af(mi 4-7)
    if (tt + 2 < NT) { stageBh(s, ktB, 0); stageBh(s, ktB, 1); }
    READ_AF2(af, 4) READ_AF2(af, 5) READ_AF2(af, 6) READ_AF2(af, 7)
    MFMA_HALF(4, af)
    // no end barrier: next iteration's gate BAR fences af reads vs A(t+2) staging
  }

  // C/D layout: col = lane&15, row = (lane>>4)*4 + reg
  OUT_T* Cz = C + (size_t)blockIdx.z * M * N;
  const int crow = (lane >> 4) * 4;
  const int ccol = lane & 15;
  #pragma unroll
  for (int mi = 0; mi < 8; ++mi) {
    #pragma unroll
    for (int ni = 0; ni < 4; ++ni) {
      #pragma unroll
      for (int r = 0; r < 4; ++r) {
        int row = m0 + wr * 128 + mi * 16 + crow + r;
        int col = n0 + wc * 64 + ni * 16 + ccol;
        Cz[(size_t)row * N + col] = (OUT_T)acc[mi][ni][r];
      }
    }
  }
#undef READ_AF2
#undef MFMA_HALF
#undef BAR
}

// ---------------- sum SPLIT fp32 partials -> OUT_T ----------------
template <typename OUT_T, int SPLIT>
__global__ __launch_bounds__(256) void reduce_partials(
    const float* __restrict__ Cp, OUT_T* __restrict__ out, int n4, int stride4) {
  int idx    = blockIdx.x * 256 + threadIdx.x;
  int stride = gridDim.x * 256;
  for (int i = idx; i < n4; i += stride) {
    float4 a = reinterpret_cast<const float4*>(Cp)[i];
    #pragma unroll
    for (int s = 1; s < SPLIT; ++s) {
      float4 b = reinterpret_cast<const float4*>(Cp)[(size_t)s * stride4 + i];
      a.x += b.x; a.y += b.y; a.z += b.z; a.w += b.w;
    }
    if constexpr (sizeof(OUT_T) == 2) {
      f16x4 h = { (_Float16)a.x, (_Float16)a.y, (_Float16)a.z, (_Float16)a.w };
      reinterpret_cast<f16x4*>(out)[i] = h;
    } else {
      reinterpret_cast<float4*>(out)[i] = a;
    }
  }
}

// ---------------- in-place row softmax over N=8192 fp16 scores ----------------
__global__ __launch_bounds__(256) void softmax_rows(_Float16* __restrict__ S, int N) {
  const int t = threadIdx.x;
  f16x8* pv = reinterpret_cast<f16x8*>(S + (size_t)blockIdx.x * N);
  float v[32];
  float m = -3.0e38f;
  #pragma unroll
  for (int i = 0; i < 4; ++i) {
    f16x8 h = pv[i * 256 + t];
    #pragma unroll
    for (int e = 0; e < 8; ++e) {
      float f = (float)h[e];
      v[i * 8 + e] = f;
      m = fmaxf(m, f);
    }
  }
  #pragma unroll
  for (int o = 32; o; o >>= 1) m = fmaxf(m, __shfl_xor(m, o));
  __shared__ float redm[4];
  if ((t & 63) == 0) redm[t >> 6] = m;
  __syncthreads();
  m = fmaxf(fmaxf(redm[0], redm[1]), fmaxf(redm[2], redm[3]));

  float s = 0.f;
  #pragma unroll
  for (int i = 0; i < 32; ++i) { v[i] = __expf(v[i] - m); s += v[i]; }
  #pragma unroll
  for (int o = 32; o; o >>= 1) s += __shfl_xor(s, o);
  __shared__ float reds[4];
  if ((t & 63) == 0) reds[t >> 6] = s;
  __syncthreads();
  s = reds[0] + reds[1] + reds[2] + reds[3];
  const float inv = 1.0f / s;

  #pragma unroll
  for (int i = 0; i < 4; ++i) {
    f16x8 h;
    #pragma unroll
    for (int e = 0; e < 8; ++e) h[e] = (_Float16)(v[i * 8 + e] * inv);
    pv[i * 256 + t] = h;
  }
}

extern "C" void kernel_launch(void* const* d_in, const int* in_sizes, int n_in,
                              void* d_out, int out_size, void* d_ws, size_t ws_size,
                              hipStream_t stream) {
  const float* x        = (const float*)d_in[0];
  const float* patterns = (const float*)d_in[1];
  float* out            = (float*)d_out;
  char* ws = (char*)d_ws;

  _Float16* Xb   = (_Float16*)(ws);                          //   8 MB [4096][1024]
  _Float16* Pb   = (_Float16*)(ws + ((size_t)8  << 20));     //  16 MB [8192][1024]
  _Float16* PbT  = (_Float16*)(ws + ((size_t)24 << 20));     //  16 MB [1024][8192]
  _Float16* S    = (_Float16*)(ws + ((size_t)40 << 20));     //  64 MB [4096][8192]
  float*    part = (float*)   (ws + ((size_t)104 << 20));    //  split x 16 MB fp32 partials

  const size_t base = (size_t)104 << 20;
  const int split = (ws_size >= base + ((size_t)64 << 20)) ? 4
                  : (ws_size >= base + ((size_t)32 << 20)) ? 2 : 1;

  convert_f32_f16<<<dim3(1024), dim3(256), 0, stream>>>(x, Xb, (B_ROWS * N_NEU) / 4);
  prep_patterns<<<dim3(N_NEU / 32, N_PAT / 32), dim3(32, 8), 0, stream>>>(
      patterns, Pb, PbT, N_PAT, N_NEU);

  const int n4 = (B_ROWS * N_NEU) / 4;
  const int stride4 = n4;

  for (int it = 0; it < 3; ++it) {
    // scores = Xb @ Pb^T  (TEMPERATURE == 1.0)  M=4096 N=8192 K=1024
    gemm_x<_Float16><<<dim3(B_ROWS / 256, N_PAT / 256, 1), dim3(512), 0, stream>>>(
        Xb, Pb, S, B_ROWS, N_PAT, N_NEU, N_NEU);
    softmax_rows<<<dim3(B_ROWS), dim3(256), 0, stream>>>(S, N_PAT);

    // new_x = probs @ P == probs @ (PbT)^T   (M=4096, N=1024, K=8192)
    if (split > 1) {
      gemm_x<float><<<dim3(B_ROWS / 256, N_NEU / 256, split), dim3(512), 0, stream>>>(
          S, PbT, part, B_ROWS, N_NEU, N_PAT, N_PAT / split);
      if (it < 2) {
        if (split == 4)
          reduce_partials<_Float16, 4><<<dim3(2048), dim3(256), 0, stream>>>(part, Xb, n4, stride4);
        else
          reduce_partials<_Float16, 2><<<dim3(2048), dim3(256), 0, stream>>>(part, Xb, n4, stride4);
      } else {
        if (split == 4)
          reduce_partials<float, 4><<<dim3(2048), dim3(256), 0, stream>>>(part, out, n4, stride4);
        else
          reduce_partials<float, 2><<<dim3(2048), dim3(256), 0, stream>>>(part, out, n4, stride4);
      }
    } else {
      gemm_x<float><<<dim3(B_ROWS / 256, N_NEU / 256, 1), dim3(512), 0, stream>>>(
          S, PbT, part, B_ROWS, N_NEU, N_PAT, N_PAT);
      if (it < 2)
        reduce_partials<_Float16, 1><<<dim3(2048), dim3(256), 0, stream>>>(part, Xb, n4, stride4);
      else
        reduce_partials<float, 1><<<dim3(2048), dim3(256), 0, stream>>>(part, out, n4, stride4);
    }
  }
}

// Round 16
// 514.855 us; speedup vs baseline: 1.0110x; 1.0110x over previous
//
#include <hip/hip_runtime.h>
#include <hip/hip_fp16.h>
#include <stdint.h>

#define B_ROWS 4096
#define N_PAT  8192
#define N_NEU  1024

typedef _Float16 f16x8 __attribute__((ext_vector_type(8)));
typedef _Float16 f16x4 __attribute__((ext_vector_type(4)));
typedef float    f32x4 __attribute__((ext_vector_type(4)));

__device__ __forceinline__ f32x4 mfma16(f16x8 a, f16x8 b, f32x4 c) {
  return __builtin_amdgcn_mfma_f32_16x16x32_f16(a, b, c, 0, 0, 0);
}

// ---------------- fp32 -> fp16 elementwise convert (vectorized) ----------------
__global__ __launch_bounds__(256) void convert_f32_f16(
    const float* __restrict__ in, _Float16* __restrict__ out, int n4) {
  int idx    = blockIdx.x * 256 + threadIdx.x;
  int stride = gridDim.x * 256;
  for (int i = idx; i < n4; i += stride) {
    float4 v = reinterpret_cast<const float4*>(in)[i];
    f16x4 h  = { (_Float16)v.x, (_Float16)v.y, (_Float16)v.z, (_Float16)v.w };
    reinterpret_cast<f16x4*>(out)[i] = h;
  }
}

// ------- patterns: single read -> Pb (f16, same layout) + PbT (f16, transposed) -------
__global__ __launch_bounds__(256) void prep_patterns(
    const float* __restrict__ in, _Float16* __restrict__ pb,
    _Float16* __restrict__ pbt, int rows, int cols) {
  __shared__ float tile[32][33];
  int c0 = blockIdx.x * 32, r0 = blockIdx.y * 32;
  int tx = threadIdx.x, ty = threadIdx.y;  // 32 x 8
  #pragma unroll
  for (int i = 0; i < 32; i += 8) {
    float v = in[(size_t)(r0 + ty + i) * cols + c0 + tx];
    tile[ty + i][tx] = v;
    pb[(size_t)(r0 + ty + i) * cols + c0 + tx] = (_Float16)v;
  }
  __syncthreads();
  #pragma unroll
  for (int i = 0; i < 32; i += 8)
    pbt[(size_t)(c0 + ty + i) * rows + r0 + tx] = (_Float16)tile[tx][ty + i];
}

// ---------------- async global->LDS, 16B per lane, wave-uniform LDS base ----------------
__device__ __forceinline__ void gload_lds16(const _Float16* g, _Float16* l) {
  __builtin_amdgcn_global_load_lds(
      (const __attribute__((address_space(1))) uint32_t*)g,
      (__attribute__((address_space(3))) uint32_t*)l, 16, 0, 0);
}

// ==== 256x256, 8 waves, XOR LDS, fine interleave + REGISTER-PIPELINED quads ====
// Measured-best GEMM structure (r13: 519.6us wall; G1 74.5us/925TF, conflicts 0).
// 2 LDS slots (128 KB), BK=64. Per K-tile: counted gate vmcnt(4) + barrier, then
// 4 phases {stage half-tile ; ds_read next af-quad into ping/pong regs ; barrier ;
// setprio(1) 16 MFMA setprio(0)}. Stage choreography ledger:
//   q0/q1: A(t+1) -> slot s^1 (A-region dead since gate)
//   q2/q3: B(t+2) -> slot s   (bf reads retired by q1's barrier)
// Gate: A(t) landed, 4 newest B-loads outstanding -> vmcnt(4); never drains to 0
// mid-loop. Compiler emits counted lgkm waits for the plain-C++ ds_reads (deps one
// phase old), so LDS latency is paid once per tile, not per phase.
template <typename OUT_T>
__global__ __launch_bounds__(512, 2) void gemm_x(
    const _Float16* __restrict__ A, const _Float16* __restrict__ Bt,
    OUT_T* __restrict__ C, int M, int N, int K, int KS) {
  __shared__ _Float16 lds[2][2][256 * 64];  // [slot][A/B][row*64]
  const int t    = threadIdx.x;
  const int lane = t & 63;
  const int w    = t >> 6;       // wave 0..7
  const int wr   = w >> 2;       // M half -> wave tile 128x64
  const int wc   = w & 3;        // N quarter
  const int m0   = blockIdx.x * 256;
  const int n0   = blockIdx.y * 256;
  const int k0   = blockIdx.z * KS;

  // staging: issue j covers rows j*64 + w*8 + (lane>>3); source granule pre-swizzled
  // (lane&7)^(row&7): LDS granule column XOR'd while the global segment per 8-lane
  // row-group stays a contiguous 128B line (keep staging coalesced - r8 lesson).
  const int srow  = w * 8 + (lane >> 3);
  const int sgran = ((lane & 7) ^ ((lane >> 3) & 7)) * 8;
  const _Float16* sA = A  + (size_t)(m0 + srow) * K + sgran + k0;
  const _Float16* sB = Bt + (size_t)(n0 + srow) * K + sgran + k0;
  const size_t rj = (size_t)64 * K;   // row jump per issue (64 rows)
  const int ldst  = w * 512;          // wave-uniform LDS elem offset within issue chunk

  const int lrow = lane & 15;  // fragment row (A) / col (B)
  const int kg   = lane >> 4;  // k-group 0..3
  const int NT   = KS >> 6;

  f32x4 acc[8][4] = {};

  auto stageAh = [&](int slot, int kt, int h) {  // half h = rows h*128..h*128+127
    gload_lds16(sA + (size_t)(2 * h)     * rj + kt, &lds[slot][0][(2 * h)     * 4096 + ldst]);
    gload_lds16(sA + (size_t)(2 * h + 1) * rj + kt, &lds[slot][0][(2 * h + 1) * 4096 + ldst]);
  };
  auto stageBh = [&](int slot, int kt, int h) {
    gload_lds16(sB + (size_t)(2 * h)     * rj + kt, &lds[slot][1][(2 * h)     * 4096 + ldst]);
    gload_lds16(sB + (size_t)(2 * h + 1) * rj + kt, &lds[slot][1][(2 * h + 1) * 4096 + ldst]);
  };

#define READ_AF(dst, MI0)                                                                   \
  { const int ar0 = wr * 128 + (MI0) * 16 + lrow;                                           \
    dst[0] = *reinterpret_cast<const f16x8*>(&As[ar0 * 64 + (((kg) ^ (ar0 & 7)) * 8)]);     \
    dst[1] = *reinterpret_cast<const f16x8*>(&As[ar0 * 64 + (((4 + kg) ^ (ar0 & 7)) * 8)]); \
    const int ar1 = ar0 + 16;                                                               \
    dst[2] = *reinterpret_cast<const f16x8*>(&As[ar1 * 64 + (((kg) ^ (ar1 & 7)) * 8)]);     \
    dst[3] = *reinterpret_cast<const f16x8*>(&As[ar1 * 64 + (((4 + kg) ^ (ar1 & 7)) * 8)]); }

#define MFMA_Q(MI0, src)                                                      \
  { __builtin_amdgcn_s_setprio(1);                                            \
    _Pragma("unroll")                                                         \
    for (int ni = 0; ni < 4; ++ni) {                                          \
      acc[MI0][ni]       = mfma16(src[0], bf[ni][0], acc[MI0][ni]);           \
      acc[MI0][ni]       = mfma16(src[1], bf[ni][1], acc[MI0][ni]);           \
      acc[(MI0) + 1][ni] = mfma16(src[2], bf[ni][0], acc[(MI0) + 1][ni]);     \
      acc[(MI0) + 1][ni] = mfma16(src[3], bf[ni][1], acc[(MI0) + 1][ni]);     \
    }                                                                         \
    __builtin_amdgcn_s_setprio(0); }

#define BAR() asm volatile("s_barrier" ::: "memory")

  // ---- prologue: B(0),A(0) -> slot0 ; B(1) -> slot1  (12 loads)
  stageBh(0, 0, 0);  stageBh(0, 0, 1);
  stageAh(0, 0, 0);  stageAh(0, 0, 1);
  stageBh(1, 64, 0); stageBh(1, 64, 1);

  for (int tt = 0; tt < NT; ++tt) {
    const int s = tt & 1;
    // ---- per-K-tile gate (counted; never 0 until the last tile)
    if (tt + 1 < NT) asm volatile("s_waitcnt vmcnt(4)" ::: "memory");
    else             asm volatile("s_waitcnt vmcnt(0)" ::: "memory");
    BAR();

    const _Float16* As = lds[s][0];
    const _Float16* Bs = lds[s][1];
    const int ktA  = (tt + 1) << 6;
    const int ktB  = (tt + 2) << 6;
    const bool pA  = (tt + 1 < NT);
    const bool pB  = (tt + 2 < NT);

    f16x8 bf[4][2], afP[4], afQ[4];
    // tile-start reads: bf (8) then af quad0 -> afP (latency paid once per tile)
    #pragma unroll
    for (int ni = 0; ni < 4; ++ni) {
      const int br = wc * 64 + ni * 16 + lrow;
      bf[ni][0] = *reinterpret_cast<const f16x8*>(&Bs[br * 64 + (((kg) ^ (br & 7)) * 8)]);
      bf[ni][1] = *reinterpret_cast<const f16x8*>(&Bs[br * 64 + (((4 + kg) ^ (br & 7)) * 8)]);
    }
    READ_AF(afP, 0)

    // q0: stage A(t+1)h0 ; prefetch af quad1 -> afQ ; MFMA quad0 (afP)
    if (pA) stageAh(s ^ 1, ktA, 0);
    READ_AF(afQ, 2)
    BAR();
    MFMA_Q(0, afP)
    // q1: stage A(t+1)h1 ; prefetch af quad2 -> afP ; MFMA quad1 (afQ)
    if (pA) stageAh(s ^ 1, ktA, 1);
    READ_AF(afP, 4)
    BAR();
    MFMA_Q(2, afQ)
    // q2: stage B(t+2)h0 ; prefetch af quad3 -> afQ ; MFMA quad2 (afP)
    if (pB) stageBh(s, ktB, 0);
    READ_AF(afQ, 6)
    BAR();
    MFMA_Q(4, afP)
    // q3: stage B(t+2)h1 ; MFMA quad3 (afQ)
    if (pB) stageBh(s, ktB, 1);
    BAR();
    MFMA_Q(6, afQ)
  }

  // C/D layout: col = lane&15, row = (lane>>4)*4 + reg
  OUT_T* Cz = C + (size_t)blockIdx.z * M * N;
  const int crow = (lane >> 4) * 4;
  const int ccol = lane & 15;
  #pragma unroll
  for (int mi = 0; mi < 8; ++mi) {
    #pragma unroll
    for (int ni = 0; ni < 4; ++ni) {
      #pragma unroll
      for (int r = 0; r < 4; ++r) {
        int row = m0 + wr * 128 + mi * 16 + crow + r;
        int col = n0 + wc * 64 + ni * 16 + ccol;
        Cz[(size_t)row * N + col] = (OUT_T)acc[mi][ni][r];
      }
    }
  }
#undef READ_AF
#undef MFMA_Q
#undef BAR
}

// ---------------- sum SPLIT fp32 partials -> OUT_T ----------------
template <typename OUT_T, int SPLIT>
__global__ __launch_bounds__(256) void reduce_partials(
    const float* __restrict__ Cp, OUT_T* __restrict__ out, int n4, int stride4) {
  int idx    = blockIdx.x * 256 + threadIdx.x;
  int stride = gridDim.x * 256;
  for (int i = idx; i < n4; i += stride) {
    float4 a = reinterpret_cast<const float4*>(Cp)[i];
    #pragma unroll
    for (int s = 1; s < SPLIT; ++s) {
      float4 b = reinterpret_cast<const float4*>(Cp)[(size_t)s * stride4 + i];
      a.x += b.x; a.y += b.y; a.z += b.z; a.w += b.w;
    }
    if constexpr (sizeof(OUT_T) == 2) {
      f16x4 h = { (_Float16)a.x, (_Float16)a.y, (_Float16)a.z, (_Float16)a.w };
      reinterpret_cast<f16x4*>(out)[i] = h;
    } else {
      reinterpret_cast<float4*>(out)[i] = a;
    }
  }
}

// ---------------- in-place row softmax over N=8192 fp16 scores ----------------
__global__ __launch_bounds__(256) void softmax_rows(_Float16* __restrict__ S, int N) {
  const int t = threadIdx.x;
  f16x8* pv = reinterpret_cast<f16x8*>(S + (size_t)blockIdx.x * N);
  float v[32];
  float m = -3.0e38f;
  #pragma unroll
  for (int i = 0; i < 4; ++i) {
    f16x8 h = pv[i * 256 + t];
    #pragma unroll
    for (int e = 0; e < 8; ++e) {
      float f = (float)h[e];
      v[i * 8 + e] = f;
      m = fmaxf(m, f);
    }
  }
  #pragma unroll
  for (int o = 32; o; o >>= 1) m = fmaxf(m, __shfl_xor(m, o));
  __shared__ float redm[4];
  if ((t & 63) == 0) redm[t >> 6] = m;
  __syncthreads();
  m = fmaxf(fmaxf(redm[0], redm[1]), fmaxf(redm[2], redm[3]));

  float s = 0.f;
  #pragma unroll
  for (int i = 0; i < 32; ++i) { v[i] = __expf(v[i] - m); s += v[i]; }
  #pragma unroll
  for (int o = 32; o; o >>= 1) s += __shfl_xor(s, o);
  __shared__ float reds[4];
  if ((t & 63) == 0) reds[t >> 6] = s;
  __syncthreads();
  s = reds[0] + reds[1] + reds[2] + reds[3];
  const float inv = 1.0f / s;

  #pragma unroll
  for (int i = 0; i < 4; ++i) {
    f16x8 h;
    #pragma unroll
    for (int e = 0; e < 8; ++e) h[e] = (_Float16)(v[i * 8 + e] * inv);
    pv[i * 256 + t] = h;
  }
}

extern "C" void kernel_launch(void* const* d_in, const int* in_sizes, int n_in,
                              void* d_out, int out_size, void* d_ws, size_t ws_size,
                              hipStream_t stream) {
  const float* x        = (const float*)d_in[0];
  const float* patterns = (const float*)d_in[1];
  float* out            = (float*)d_out;
  char* ws = (char*)d_ws;

  _Float16* Xb   = (_Float16*)(ws);                          //   8 MB [4096][1024]
  _Float16* Pb   = (_Float16*)(ws + ((size_t)8  << 20));     //  16 MB [8192][1024]
  _Float16* PbT  = (_Float16*)(ws + ((size_t)24 << 20));     //  16 MB [1024][8192]
  _Float16* S    = (_Float16*)(ws + ((size_t)40 << 20));     //  64 MB [4096][8192]
  float*    part = (float*)   (ws + ((size_t)104 << 20));    //  split x 16 MB fp32 partials

  const size_t base = (size_t)104 << 20;
  const int split = (ws_size >= base + ((size_t)64 << 20)) ? 4
                  : (ws_size >= base + ((size_t)32 << 20)) ? 2 : 1;

  convert_f32_f16<<<dim3(1024), dim3(256), 0, stream>>>(x, Xb, (B_ROWS * N_NEU) / 4);
  prep_patterns<<<dim3(N_NEU / 32, N_PAT / 32), dim3(32, 8), 0, stream>>>(
      patterns, Pb, PbT, N_PAT, N_NEU);

  const int n4 = (B_ROWS * N_NEU) / 4;
  const int stride4 = n4;

  for (int it = 0; it < 3; ++it) {
    // scores = Xb @ Pb^T  (TEMPERATURE == 1.0)  M=4096 N=8192 K=1024
    gemm_x<_Float16><<<dim3(B_ROWS / 256, N_PAT / 256, 1), dim3(512), 0, stream>>>(
        Xb, Pb, S, B_ROWS, N_PAT, N_NEU, N_NEU);
    softmax_rows<<<dim3(B_ROWS), dim3(256), 0, stream>>>(S, N_PAT);

    // new_x = probs @ P == probs @ (PbT)^T   (M=4096, N=1024, K=8192)
    if (split > 1) {
      gemm_x<float><<<dim3(B_ROWS / 256, N_NEU / 256, split), dim3(512), 0, stream>>>(
          S, PbT, part, B_ROWS, N_NEU, N_PAT, N_PAT / split);
      if (it < 2) {
        if (split == 4)
          reduce_partials<_Float16, 4><<<dim3(2048), dim3(256), 0, stream>>>(part, Xb, n4, stride4);
        else
          reduce_partials<_Float16, 2><<<dim3(2048), dim3(256), 0, stream>>>(part, Xb, n4, stride4);
      } else {
        if (split == 4)
          reduce_partials<float, 4><<<dim3(2048), dim3(256), 0, stream>>>(part, out, n4, stride4);
        else
          reduce_partials<float, 2><<<dim3(2048), dim3(256), 0, stream>>>(part, out, n4, stride4);
      }
    } else {
      gemm_x<float><<<dim3(B_ROWS / 256, N_NEU / 256, 1), dim3(512), 0, stream>>>(
          S, PbT, part, B_ROWS, N_NEU, N_PAT, N_PAT);
      if (it < 2)
        reduce_partials<_Float16, 1><<<dim3(2048), dim3(256), 0, stream>>>(part, Xb, n4, stride4);
      else
        reduce_partials<float, 1><<<dim3(2048), dim3(256), 0, stream>>>(part, out, n4, stride4);
    }
  }
}